// Round 1
// baseline (264.376 us; speedup 1.0000x reference)
//
#include <hip/hip_runtime.h>

#define NMS_T    0.7f
#define SCORE_T  0.05f
#define MIN_SZ   0.001f
#define MAXK     250
#define NEGV     -1e30f
#define NB       2048
#define NIMG     8

__device__ __forceinline__ bool iou_gt(const float4 a, const float aa,
                                       const float4 b, const float ba) {
  // exact reference arithmetic: inter / (area_i + area_j - inter + 1e-12) > 0.7
  float xx1 = fmaxf(a.x, b.x);
  float yy1 = fmaxf(a.y, b.y);
  float xx2 = fminf(a.z, b.z);
  float yy2 = fminf(a.w, b.w);
  float iw = fmaxf(xx2 - xx1, 0.0f);
  float ih = fmaxf(yy2 - yy1, 0.0f);
  float inter = iw * ih;
  float denom = aa + ba - inter + 1e-12f;   // f32 add commutative -> matches ref order
  return (inter / denom) > NMS_T;           // IEEE f32 divide (no fast-math)
}

__global__ __launch_bounds__(256) void filter_rois_kernel(
    const float* __restrict__ proposals,
    const float* __restrict__ scores,
    float* __restrict__ out) {
  __shared__ unsigned long long s_key[NB];  // 16 KB
  __shared__ float4 s_box[NB];              // 32 KB
  __shared__ float s_sc[NB];                // 8 KB  (masked score by local idx)
  __shared__ int s_kidx[256];               // kept local indices (<=250)
  __shared__ int s_nk;

  const int tid = threadIdx.x;
  const int img = blockIdx.x;

  // ---- stage 0/1/2: transform + clip + validity, build sort keys ----
  for (int l = tid; l < NB; l += 256) {
    int g = img * NB + l;
    float4 p = reinterpret_cast<const float4*>(proposals)[g];
    float s = scores[g];
    // sigmoid in double -> correctly-rounded f32 sigma, then f32 *2-1 like ref
    double e = exp(-(double)s);
    float sig = (float)(1.0 / (1.0 + e));
    float sp = sig * 2.0f - 1.0f;
    float x1 = fminf(fmaxf(p.x, 0.0f), 512.0f);
    float y1 = fminf(fmaxf(p.y, 0.0f), 512.0f);
    float x2 = fminf(fmaxf(p.z, 0.0f), 512.0f);
    float y2 = fminf(fmaxf(p.w, 0.0f), 512.0f);
    bool valid = (sp >= SCORE_T) && ((x2 - x1) >= MIN_SZ) && ((y2 - y1) >= MIN_SZ);
    float m = valid ? sp : NEGV;
    // order-preserving float->uint, inverted for descending sort; idx in low bits
    unsigned int u = __float_as_uint(m);
    unsigned int ob = (u & 0x80000000u) ? ~u : (u | 0x80000000u);
    unsigned int inv = ~ob;
    s_key[l] = ((unsigned long long)inv << 32) | (unsigned int)l;
    s_box[l] = make_float4(x1, y1, x2, y2);
    s_sc[l] = m;
  }
  __syncthreads();

  // ---- stable sort: ascending on 64-bit key == descending score, ties by idx ----
  for (unsigned int k = 2; k <= NB; k <<= 1) {
    for (unsigned int j = k >> 1; j > 0; j >>= 1) {
      for (unsigned int i = tid; i < NB; i += 256) {
        unsigned int ixj = i ^ j;
        if (ixj > i) {
          unsigned long long a = s_key[i];
          unsigned long long b = s_key[ixj];
          bool up = ((i & k) == 0);
          bool sw = up ? (a > b) : (a < b);
          if (sw) { s_key[i] = b; s_key[ixj] = a; }
        }
      }
      __syncthreads();
    }
  }

  // ---- stage 3: greedy NMS, wave 0 only; kept list in registers (4/lane) ----
  if (tid < 64) {
    const int lane = tid;
    float4 kb0 = make_float4(0,0,0,0), kb1 = kb0, kb2 = kb0, kb3 = kb0;
    float ka0 = 0.f, ka1 = 0.f, ka2 = 0.f, ka3 = 0.f;
    int nk = 0;
    for (int c = 0; c < NB && nk < MAXK; ++c) {
      int idx = (int)(s_key[c] & 0xffffffffu);
      float sp = s_sc[idx];
      if (!(sp > -1e29f)) break;   // sorted: rest are invalid
      float4 bc = s_box[idx];
      float ca = (bc.z - bc.x) * (bc.w - bc.y);
      bool sup = false;
      if (lane < nk)        sup = sup || iou_gt(bc, ca, kb0, ka0);
      if (lane + 64 < nk)   sup = sup || iou_gt(bc, ca, kb1, ka1);
      if (lane + 128 < nk)  sup = sup || iou_gt(bc, ca, kb2, ka2);
      if (lane + 192 < nk)  sup = sup || iou_gt(bc, ca, kb3, ka3);
      if (__any(sup) == 0) {
        if (lane == (nk & 63)) {
          int r = nk >> 6;
          if      (r == 0) { kb0 = bc; ka0 = ca; }
          else if (r == 1) { kb1 = bc; ka1 = ca; }
          else if (r == 2) { kb2 = bc; ka2 = ca; }
          else             { kb3 = bc; ka3 = ca; }
        }
        if (lane == 0) s_kidx[nk] = idx;
        ++nk;
      }
    }
    if (lane == 0) s_nk = nk;
  }
  __syncthreads();

  // ---- stage 4: top-250 per image (kept list is already score-ordered) ----
  const int nk = s_nk;
  for (int o = tid; o < MAXK; o += 256) {
    float4 bo = make_float4(0,0,0,0);
    float so = 0.0f, vo = 0.0f;
    if (o < nk) {
      int idx = s_kidx[o];
      bo = s_box[idx];
      so = s_sc[idx];
      vo = 1.0f;
    }
    reinterpret_cast<float4*>(out)[img * MAXK + o] = bo;                       // boxes [8,250,4]
    out[NIMG * MAXK * 4 + img * MAXK + o] = so;                                // scores [8,250]
    out[NIMG * MAXK * 4 + NIMG * MAXK + img * MAXK + o] = vo;                  // valid [8,250]
  }
}

extern "C" void kernel_launch(void* const* d_in, const int* in_sizes, int n_in,
                              void* d_out, int out_size, void* d_ws, size_t ws_size,
                              hipStream_t stream) {
  const float* proposals = (const float*)d_in[0];
  const float* scores    = (const float*)d_in[1];
  float* out             = (float*)d_out;
  filter_rois_kernel<<<dim3(NIMG), dim3(256), 0, stream>>>(proposals, scores, out);
}

// Round 2
// 129.908 us; speedup vs baseline: 2.0351x; 2.0351x over previous
//
#include <hip/hip_runtime.h>

#define NMS_T    0.7f
#define SCORE_T  0.05f
#define MIN_SZ   0.001f
#define MAXK     250
#define NEGV     -1e30f
#define NB       2048
#define NIMG     8
#define NT       512
#define NW       (NT / 64)

typedef unsigned long long u64;
typedef unsigned int u32;

// inverse of the order-preserving float->u32 descending-sort transform
__device__ __forceinline__ float sp_from_key(u32 inv) {
  return (inv & 0x80000000u) ? __uint_as_float(inv)
                             : __uint_as_float((~inv) ^ 0x80000000u);
}

__device__ __forceinline__ bool iou_gt(const float4 a, float aa,
                                       const float4 b, float ba) {
  // exact reference arithmetic: inter / (area_i + area_j - inter + 1e-12) > 0.7
  float xx1 = fmaxf(a.x, b.x);
  float yy1 = fmaxf(a.y, b.y);
  float xx2 = fminf(a.z, b.z);
  float yy2 = fminf(a.w, b.w);
  float inter = fmaxf(xx2 - xx1, 0.0f) * fmaxf(yy2 - yy1, 0.0f);
  float denom = aa + ba - inter + 1e-12f;  // f32 add commutative
  return (inter / denom) > NMS_T;          // IEEE f32 divide
}

__global__ __launch_bounds__(NT) void filter_rois_kernel(
    const float* __restrict__ proposals,
    const float* __restrict__ scores,
    float* __restrict__ out) {
  __shared__ u64 s_key[NB];        // 16 KB  (inv_score<<32 | local_idx)
  __shared__ float4 s_box[NB];     // 32 KB  (clipped boxes by local idx)
  __shared__ float4 s_kbox[MAXK];  // kept boxes (score order)
  __shared__ float s_karea[MAXK];
  __shared__ float s_ksc[MAXK];
  __shared__ float4 s_cbox[64];    // current chunk candidates
  __shared__ float s_carea[64];
  __shared__ float s_csp[64];
  __shared__ u64 s_pm[NW][64];     // per-wave partial within-chunk masks
  __shared__ u64 s_bw[NW];         // per-wave kept-suppression ballots
  __shared__ int s_nk;

  const int tid = threadIdx.x;
  const int img = blockIdx.x;
  const int w = tid >> 6;
  const int lane = tid & 63;

  // ---- stage 0/1/2: transform + clip + validity, build sort keys ----
  for (int l = tid; l < NB; l += NT) {
    int g = img * NB + l;
    float4 p = reinterpret_cast<const float4*>(proposals)[g];
    float s = scores[g];
    double e = exp(-(double)s);
    float sig = (float)(1.0 / (1.0 + e));
    float sp = sig * 2.0f - 1.0f;
    float x1 = fminf(fmaxf(p.x, 0.0f), 512.0f);
    float y1 = fminf(fmaxf(p.y, 0.0f), 512.0f);
    float x2 = fminf(fmaxf(p.z, 0.0f), 512.0f);
    float y2 = fminf(fmaxf(p.w, 0.0f), 512.0f);
    bool valid = (sp >= SCORE_T) && ((x2 - x1) >= MIN_SZ) && ((y2 - y1) >= MIN_SZ);
    float m = valid ? sp : NEGV;
    u32 u = __float_as_uint(m);
    u32 ob = (u & 0x80000000u) ? ~u : (u | 0x80000000u);
    u32 inv = ~ob;  // ascending sort on inv == descending on score, idx ties asc
    s_key[l] = ((u64)inv << 32) | (u32)l;
    s_box[l] = make_float4(x1, y1, x2, y2);
  }
  if (tid == 0) s_nk = 0;
  __syncthreads();

  // ---- stable bitonic sort, ascending on 64-bit key ----
  for (u32 k = 2; k <= NB; k <<= 1) {
    for (u32 j = k >> 1; j > 0; j >>= 1) {
      for (u32 i = tid; i < NB; i += NT) {
        u32 ixj = i ^ j;
        if (ixj > i) {
          u64 a = s_key[i];
          u64 b = s_key[ixj];
          bool up = ((i & k) == 0);
          bool sw = up ? (a > b) : (a < b);
          if (sw) { s_key[i] = b; s_key[ixj] = a; }
        }
      }
      __syncthreads();
    }
  }

  // ---- stage 3: chunk-parallel greedy NMS (64 candidates per chunk) ----
  for (int t = 0; t < NB / 64; ++t) {
    __syncthreads();                   // kept list + s_nk from prev chunk visible
    const int nk = s_nk;
    if (nk >= MAXK) break;             // uniform
    const int c0 = t * 64;
    if (tid < 64) {                    // stage chunk candidates
      u64 key = s_key[c0 + tid];
      u32 idx = (u32)(key & 0xffffffffu);
      float sp = sp_from_key((u32)(key >> 32));
      float4 b = s_box[idx];
      s_cbox[tid] = b;
      s_carea[tid] = (b.z - b.x) * (b.w - b.y);
      s_csp[tid] = sp;
    }
    __syncthreads();
    if (s_csp[0] < -1e29f) break;      // sorted: whole chunk invalid (uniform)

    const float4 cb = s_cbox[lane];
    const float ca = s_carea[lane];
    const float csp = s_csp[lane];
    const bool valid = csp > -1e29f;

    // (a) suppression vs kept list, split across waves
    bool sup = false;
    for (int j = w; j < nk; j += NW)
      sup = sup || iou_gt(cb, ca, s_kbox[j], s_karea[j]);
    u64 bsup = __ballot(sup);
    if (lane == 0) s_bw[w] = bsup;

    // (b) within-chunk pairwise triangle, bit positions j == w (mod NW)
    u64 pm = 0;
    for (int j = w; j < 64; j += NW) {
      if (j < lane && iou_gt(cb, ca, s_cbox[j], s_carea[j]))
        pm |= 1ull << j;
    }
    s_pm[w][lane] = pm;
    __syncthreads();

    // combine masks; every wave replays the identical scalar sweep
    u64 m = 0;
    for (int q = 0; q < NW; ++q) m |= s_pm[q][lane];
    u64 supmask = 0;
    for (int q = 0; q < NW; ++q) supmask |= s_bw[q];
    u64 alive = __ballot(valid) & ~supmask;
    u64 kept = 0;
    while (alive) {
      int f = (int)__ffsll(alive) - 1;
      kept |= 1ull << f;
      alive &= ~(1ull << f);
      u64 row = __ballot((m >> f) & 1ull);  // who f suppresses
      alive &= ~row;
    }

    // append kept (wave 0 only); truncate at MAXK
    if (w == 0) {
      int space = MAXK - nk;
      int npc = (int)__popcll(kept);
      int nnew = npc < space ? npc : space;
      if ((kept >> lane) & 1ull) {
        int rank = (int)__popcll(kept & ((1ull << lane) - 1ull));
        if (rank < space) {
          s_kbox[nk + rank] = cb;
          s_karea[nk + rank] = ca;
          s_ksc[nk + rank] = csp;
        }
      }
      if (lane == 0) s_nk = nk + nnew;
    }
  }
  __syncthreads();

  // ---- stage 4: top-250 (kept list is already in score order) ----
  const int nk = s_nk;
  for (int o = tid; o < MAXK; o += NT) {
    float4 bo = make_float4(0.f, 0.f, 0.f, 0.f);
    float so = 0.0f, vo = 0.0f;
    if (o < nk) {
      bo = s_kbox[o];
      so = s_ksc[o];
      vo = 1.0f;
    }
    reinterpret_cast<float4*>(out)[img * MAXK + o] = bo;          // boxes [8,250,4]
    out[NIMG * MAXK * 4 + img * MAXK + o] = so;                   // scores [8,250]
    out[NIMG * MAXK * 4 + NIMG * MAXK + img * MAXK + o] = vo;     // valid [8,250]
  }
}

extern "C" void kernel_launch(void* const* d_in, const int* in_sizes, int n_in,
                              void* d_out, int out_size, void* d_ws, size_t ws_size,
                              hipStream_t stream) {
  const float* proposals = (const float*)d_in[0];
  const float* scores    = (const float*)d_in[1];
  float* out             = (float*)d_out;
  filter_rois_kernel<<<dim3(NIMG), dim3(NT), 0, stream>>>(proposals, scores, out);
}

// Round 3
// 87.281 us; speedup vs baseline: 3.0290x; 1.4884x over previous
//
#include <hip/hip_runtime.h>

#define NMS_T    0.7f
#define SCORE_T  0.05f
#define MIN_SZ   0.001f
#define MAXK     250
#define NEGV     -1e30f
#define NB       2048
#define NIMG     8
#define NT       512
#define NW       (NT / 64)

typedef unsigned long long u64;
typedef unsigned int u32;

// inverse of the order-preserving float->u32 descending-sort transform
__device__ __forceinline__ float sp_from_key(u32 inv) {
  return (inv & 0x80000000u) ? __uint_as_float(inv)
                             : __uint_as_float((~inv) ^ 0x80000000u);
}

__device__ __forceinline__ bool iou_gt(const float4 a, float aa,
                                       const float4 b, float ba) {
  float xx1 = fmaxf(a.x, b.x);
  float yy1 = fmaxf(a.y, b.y);
  float xx2 = fminf(a.z, b.z);
  float yy2 = fminf(a.w, b.w);
  float inter = fmaxf(xx2 - xx1, 0.0f) * fmaxf(yy2 - yy1, 0.0f);
  float denom = aa + ba - inter + 1e-12f;
  return (inter / denom) > NMS_T;   // IEEE f32 divide
}

__device__ __forceinline__ u64 shflx64(u64 v, int mask) {
  return (u64)__shfl_xor((unsigned long long)v, mask, 64);
}

__device__ __forceinline__ u64 ce_min(u64 a, u64 b) { return a < b ? a : b; }
__device__ __forceinline__ u64 ce_max(u64 a, u64 b) { return a > b ? a : b; }

__global__ __launch_bounds__(NT) void filter_rois_kernel(
    const float* __restrict__ proposals,
    const float* __restrict__ scores,
    float* __restrict__ out) {
  __shared__ u64 s_key[NB];        // compacted keys (inv<<32 | orig local idx)
  __shared__ float4 s_box[NB];     // clipped boxes by original local idx
  __shared__ int s_wcnt[32];       // per-64-chunk valid counts -> excl prefix
  __shared__ int s_nv;
  __shared__ float4 s_kbox[MAXK];
  __shared__ float s_karea[MAXK];
  __shared__ float s_ksc[MAXK];
  __shared__ float4 s_cbox[64];
  __shared__ float s_carea[64];
  __shared__ float s_csp[64];
  __shared__ u64 s_pm[NW][64];
  __shared__ u64 s_bw[NW];
  __shared__ int s_nk;

  const int tid = threadIdx.x;
  const int img = blockIdx.x;
  const int w = tid >> 6;
  const int lane = tid & 63;

  // ---- stage 0/1/2: transform + clip + validity (keys kept in registers) ----
  u32 inv_r[4];
  int rank_r[4];
  bool valid_r[4];
  for (int r = 0; r < 4; ++r) {
    int l = r * NT + tid;                 // chunk (r*8+w), lane ascending = idx ascending
    int g = img * NB + l;
    float4 p = reinterpret_cast<const float4*>(proposals)[g];
    float s = scores[g];
    double e = exp(-(double)s);
    float sig = (float)(1.0 / (1.0 + e));
    float sp = sig * 2.0f - 1.0f;
    float x1 = fminf(fmaxf(p.x, 0.0f), 512.0f);
    float y1 = fminf(fmaxf(p.y, 0.0f), 512.0f);
    float x2 = fminf(fmaxf(p.z, 0.0f), 512.0f);
    float y2 = fminf(fmaxf(p.w, 0.0f), 512.0f);
    bool valid = (sp >= SCORE_T) && ((x2 - x1) >= MIN_SZ) && ((y2 - y1) >= MIN_SZ);
    s_box[l] = make_float4(x1, y1, x2, y2);
    u32 u = __float_as_uint(valid ? sp : NEGV);
    u32 ob = (u & 0x80000000u) ? ~u : (u | 0x80000000u);
    inv_r[r] = ~ob;
    valid_r[r] = valid;
    u64 b = __ballot(valid);
    if (lane == 0) s_wcnt[r * 8 + w] = (int)__popcll(b);
    rank_r[r] = (int)__popcll(b & ((1ull << lane) - 1ull));
  }
  __syncthreads();

  // exclusive prefix over the 32 chunk counts (wave 0, lanes 0..31)
  if (tid < 32) {
    int v = s_wcnt[tid];
    int inc = v;
    for (int d = 1; d < 32; d <<= 1) {
      int t2 = __shfl_up(inc, d, 64);
      if (tid >= d) inc += t2;
    }
    s_wcnt[tid] = inc - v;
    if (tid == 31) s_nv = inc;
  }
  __syncthreads();

  // stable scatter of valid keys + tail fill
  for (int r = 0; r < 4; ++r) {
    if (valid_r[r]) {
      int l = r * NT + tid;
      int pos = s_wcnt[r * 8 + w] + rank_r[r];
      s_key[pos] = ((u64)inv_r[r] << 32) | (u32)l;
    }
  }
  const int Nv = s_nv;
  const int n = (Nv <= 1024) ? 1024 : NB;
  for (int i2 = Nv + tid; i2 < n; i2 += NT) s_key[i2] = ~0ull;
  if (tid == 0) s_nk = 0;
  __syncthreads();

  // ---- stable sort (ascending on 64-bit key == descending score) ----
  if (Nv <= 1024) {
    // register bitonic: 2 keys/thread; j<=64 via shuffles, j>=128 via LDS (6 passes)
    const u32 i0 = 2 * tid, i1 = 2 * tid + 1;
    u64 e0 = s_key[i0], e1 = s_key[i1];
    for (u32 k = 2; k <= 1024; k <<= 1) {
      for (u32 j = k >> 1; j >= 1; j >>= 1) {
        bool asc = ((i0 & k) == 0);
        if (j == 1) {
          u64 lo = ce_min(e0, e1), hi = ce_max(e0, e1);
          e0 = asc ? lo : hi;
          e1 = asc ? hi : lo;
        } else if (j <= 64) {
          bool lower = ((i0 & j) == 0);
          bool takemin = (lower == asc);
          u64 p0 = shflx64(e0, (int)(j >> 1));
          u64 p1 = shflx64(e1, (int)(j >> 1));
          e0 = takemin ? ce_min(e0, p0) : ce_max(e0, p0);
          e1 = takemin ? ce_min(e1, p1) : ce_max(e1, p1);
        } else {
          __syncthreads();             // protect prior reads
          s_key[i0] = e0;
          s_key[i1] = e1;
          __syncthreads();
          u64 p0 = s_key[i0 ^ j], p1 = s_key[i1 ^ j];
          bool lower = ((i0 & j) == 0);
          bool takemin = (lower == asc);
          e0 = takemin ? ce_min(e0, p0) : ce_max(e0, p0);
          e1 = takemin ? ce_min(e1, p1) : ce_max(e1, p1);
        }
      }
    }
    __syncthreads();
    s_key[i0] = e0;
    s_key[i1] = e1;
  } else {
    // rare fallback: plain LDS bitonic over 2048
    for (u32 k = 2; k <= NB; k <<= 1) {
      for (u32 j = k >> 1; j > 0; j >>= 1) {
        for (u32 i = tid; i < NB; i += NT) {
          u32 ixj = i ^ j;
          if (ixj > i) {
            u64 a = s_key[i];
            u64 b = s_key[ixj];
            bool up = ((i & k) == 0);
            bool sw = up ? (a > b) : (a < b);
            if (sw) { s_key[i] = b; s_key[ixj] = a; }
          }
        }
        __syncthreads();
      }
    }
  }

  // ---- stage 3: chunk-parallel greedy NMS ----
  for (int t = 0; t * 64 < Nv; ++t) {
    __syncthreads();                 // sorted keys / kept list visible
    const int nk = s_nk;
    if (nk >= MAXK) break;
    const int c0 = t * 64;
    if (tid < 64) {
      int ci = c0 + tid;
      if (ci < Nv) {
        u64 key = s_key[ci];
        u32 idx = (u32)(key & 0xffffffffu);
        float4 b = s_box[idx];
        s_cbox[tid] = b;
        s_carea[tid] = (b.z - b.x) * (b.w - b.y);
        s_csp[tid] = sp_from_key((u32)(key >> 32));
      } else {
        s_csp[tid] = NEGV;
      }
    }
    __syncthreads();

    const bool valid = (c0 + lane) < Nv;
    const float4 cb = s_cbox[lane];
    const float ca = s_carea[lane];
    const float csp = s_csp[lane];

    // (a) suppression vs kept list, split across waves
    bool sup = false;
    for (int j = w; j < nk; j += NW)
      sup = sup || iou_gt(cb, ca, s_kbox[j], s_karea[j]);
    if (lane == 0) s_bw[w] = 0;      // ensure defined before ballot store
    u64 bsup = __ballot(sup);
    if (lane == 0) s_bw[w] = bsup;

    // (b) within-chunk triangle, split across waves
    u64 pm = 0;
    for (int j = w; j < 64; j += NW) {
      if (j < lane && iou_gt(cb, ca, s_cbox[j], s_carea[j]))
        pm |= 1ull << j;
    }
    s_pm[w][lane] = pm;
    __syncthreads();

    // combine; bulk-keep sweep (every wave replays identically)
    u64 m = 0;
    for (int q = 0; q < NW; ++q) m |= s_pm[q][lane];
    u64 supmask = 0;
    for (int q = 0; q < NW; ++q) supmask |= s_bw[q];
    u64 alive = __ballot(valid) & ~supmask;
    u64 m2 = m & alive;              // potential suppressors of this lane
    u64 kept = 0;
    while (alive) {
      m2 &= (alive | kept);
      u64 targets = __ballot(m2 != 0) & alive;
      if (!targets) { kept |= alive; break; }
      int tb = (int)__ffsll((unsigned long long)targets) - 1;
      u64 below = ((1ull << tb) - 1ull) & alive;
      kept |= below;
      alive &= ~below;
      u64 supnow = __ballot((m2 & kept) != 0);
      if (!((supnow >> tb) & 1ull)) kept |= (1ull << tb);
      alive &= ~(1ull << tb);
    }

    // append kept (wave 0), truncate at MAXK
    if (w == 0) {
      int space = MAXK - nk;
      int npc = (int)__popcll(kept);
      int nnew = npc < space ? npc : space;
      if ((kept >> lane) & 1ull) {
        int rank = (int)__popcll(kept & ((1ull << lane) - 1ull));
        if (rank < space) {
          s_kbox[nk + rank] = cb;
          s_karea[nk + rank] = ca;
          s_ksc[nk + rank] = csp;
        }
      }
      if (lane == 0) s_nk = nk + nnew;
    }
  }
  __syncthreads();

  // ---- stage 4: top-250 (kept list already in score order) ----
  const int nk = s_nk;
  for (int o = tid; o < MAXK; o += NT) {
    float4 bo = make_float4(0.f, 0.f, 0.f, 0.f);
    float so = 0.0f, vo = 0.0f;
    if (o < nk) {
      bo = s_kbox[o];
      so = s_ksc[o];
      vo = 1.0f;
    }
    reinterpret_cast<float4*>(out)[img * MAXK + o] = bo;          // boxes [8,250,4]
    out[NIMG * MAXK * 4 + img * MAXK + o] = so;                   // scores [8,250]
    out[NIMG * MAXK * 4 + NIMG * MAXK + img * MAXK + o] = vo;     // valid [8,250]
  }
}

extern "C" void kernel_launch(void* const* d_in, const int* in_sizes, int n_in,
                              void* d_out, int out_size, void* d_ws, size_t ws_size,
                              hipStream_t stream) {
  const float* proposals = (const float*)d_in[0];
  const float* scores    = (const float*)d_in[1];
  float* out             = (float*)d_out;
  filter_rois_kernel<<<dim3(NIMG), dim3(NT), 0, stream>>>(proposals, scores, out);
}